// Round 3
// baseline (257.577 us; speedup 1.0000x reference)
//
#include <hip/hip_runtime.h>

#define CLS   160          // CLASS_NUM * NUM_PRED
#define TOPKN 1000
#define N0 147456
#define N1 36864
#define N2 9216
#define N3 2304
#define N4 576
#define NROWS (N0 + N1 + N2 + N3)   // 195840 anchors needing top-k keys
#define BD1 N0
#define BD2 (N0 + N1)
#define BD3 (N0 + N1 + N2)
#define NSEL (4 * TOPKN + N4)       // 4576 selected anchors
#define NBINS 65536
#define CAND_CAP 2048

__device__ __forceinline__ unsigned sortable(float f) {
    unsigned u = __float_as_uint(f);
    return (u & 0x80000000u) ? ~u : (u | 0x80000000u);
}

// ---------------------------------------------------------------------------
// K1: ruler keys only, NO atomics. 8 lanes per row, 5 float4 loads per lane
// (one vector-load instruction covers 8 complete rows). 3-step shuffle
// reduce within each 8-lane group. Grid-stride over row-groups of 8.
// ---------------------------------------------------------------------------
__global__ __launch_bounds__(256) void k_ruler(
    const float* __restrict__ c0, const float* __restrict__ c1,
    const float* __restrict__ c2, const float* __restrict__ c3,
    unsigned* __restrict__ keys)
{
    int tid  = blockIdx.x * 256 + threadIdx.x;
    int wv   = tid >> 6;
    int lane = tid & 63;
    int sub  = lane >> 3;   // row within group of 8
    int col  = lane & 7;    // float4 column group
    const int NW = 1530 * 4;
    for (int g = wv; g < NROWS / 8; g += NW) {
        int r0 = g * 8;     // 8 rows, always within one level (sizes % 8 == 0)
        const float* cb; int lr;
        if (r0 < BD1)      { cb = c0; lr = r0; }
        else if (r0 < BD2) { cb = c1; lr = r0 - BD1; }
        else if (r0 < BD3) { cb = c2; lr = r0 - BD2; }
        else               { cb = c3; lr = r0 - BD3; }
        const float4* p = (const float4*)cb + (size_t)(lr + sub) * 40 + col;
        float m = -3.4e38f;
        #pragma unroll
        for (int k = 0; k < 5; ++k) {
            float4 v = p[8 * k];
            m = fmaxf(m, fmaxf(fmaxf(v.x, v.y), fmaxf(v.z, v.w)));
        }
        m = fmaxf(m, __shfl_xor(m, 1));
        m = fmaxf(m, __shfl_xor(m, 2));
        m = fmaxf(m, __shfl_xor(m, 4));
        if (col == 0) keys[r0 + sub] = sortable(m);
    }
}

// ---------------------------------------------------------------------------
// K2: ownership histogram — NO memset, NO global atomics. 64 blocks =
// (level, 4096-bin segment). Each block scans its whole level's keys
// (L2-resident), counts its segment's bins in LDS, then PLAIN-STORES the
// 4096 bins (zeros included). Full hist coverage every call.
// ---------------------------------------------------------------------------
__global__ __launch_bounds__(256) void k_hist(const unsigned* __restrict__ keys,
                                              unsigned* __restrict__ hist)
{
    int b     = blockIdx.x;      // 64 blocks
    int level = b >> 4;
    unsigned seg = b & 15;
    __shared__ unsigned cnt[4096];
    for (int i = threadIdx.x; i < 4096; i += 256) cnt[i] = 0;
    __syncthreads();
    int base, n;
    switch (level) {
        case 0:  base = 0;   n = N0; break;
        case 1:  base = BD1; n = N1; break;
        case 2:  base = BD2; n = N2; break;
        default: base = BD3; n = N3; break;
    }
    const unsigned* kp = keys + base;
    unsigned lo = seg << 12;
    for (int i = threadIdx.x; i < n; i += 256) {
        unsigned bin = kp[i] >> 16;
        if ((bin >> 12) == seg) atomicAdd(&cnt[bin - lo], 1u);
    }
    __syncthreads();
    unsigned* h = hist + level * NBINS + lo;
    for (int i = threadIdx.x; i < 4096; i += 256) h[i] = cnt[i];
}

// ---------------------------------------------------------------------------
// K3: per level (4 blocks), scan histogram descending to find the bin holding
// the 1000th-largest key. Threshold = lower edge of that bin. Also zero the
// candidate counter for this call.
// ---------------------------------------------------------------------------
__global__ __launch_bounds__(1024) void k_decide(const unsigned* __restrict__ hist,
                                                 unsigned* __restrict__ ctrl)
{
    int level = blockIdx.x;
    const unsigned* h = hist + level * NBINS;
    int t = threadIdx.x;
    __shared__ unsigned s[1024];

    unsigned sum = 0;
    #pragma unroll 4
    for (int i = 0; i < 64; ++i) sum += h[t * 64 + i];
    s[t] = sum;
    __syncthreads();

    // suffix sums: s[t] = sum over chunks t..1023 (Hillis-Steele)
    for (int off = 1; off < 1024; off <<= 1) {
        unsigned v   = s[t];
        unsigned add = (t + off < 1024) ? s[t + off] : 0u;
        __syncthreads();
        s[t] = v + add;
        __syncthreads();
    }

    // exactly one thread has suf[t] >= K and suf[t+1] < K (suf nonincreasing)
    if (s[t] >= TOPKN && (t == 1023 || s[t + 1] < TOPKN)) {
        unsigned cum = (t == 1023) ? 0u : s[t + 1];
        int edge = t * 64;
        for (int b = t * 64 + 63; b >= t * 64; --b) {
            cum += h[b];
            if (cum >= TOPKN) { edge = b; break; }
        }
        ctrl[level]     = ((unsigned)edge) << 16;  // threshold key
        ctrl[4 + level] = 0u;                      // reset candidate counter
    }
}

// ---------------------------------------------------------------------------
// K4: compact (key, local_idx) with key >= threshold. Wave-aggregated
// counter atomic: one atomicAdd per wave with >=1 candidate. Level
// boundaries are all multiples of 64, so a wave never straddles levels.
// ---------------------------------------------------------------------------
__global__ __launch_bounds__(256) void k_compact(const unsigned* __restrict__ keys,
                                                 unsigned* __restrict__ ctrl,
                                                 uint2* __restrict__ cand)
{
    int w = blockIdx.x * 256 + threadIdx.x;
    int lane = threadIdx.x & 63;
    int level, base;
    if (w < BD1)      { level = 0; base = 0;   }
    else if (w < BD2) { level = 1; base = BD1; }
    else if (w < BD3) { level = 2; base = BD2; }
    else              { level = 3; base = BD3; }
    unsigned key = keys[w];
    bool pass = key >= ctrl[level];
    unsigned long long mask = __ballot(pass);
    if (pass) {
        int leader    = __ffsll((long long)mask) - 1;
        unsigned tot  = (unsigned)__popcll(mask);
        unsigned rank = (unsigned)__popcll(mask & ((1ull << lane) - 1ull));
        unsigned bpos = 0;
        if (lane == leader) bpos = atomicAdd(&ctrl[4 + level], tot);
        bpos = (unsigned)__shfl((int)bpos, leader);
        unsigned pos = bpos + rank;
        if (pos < CAND_CAP)
            cand[level * CAND_CAP + pos] = make_uint2(key, (unsigned)(w - base));
    }
}

// ---------------------------------------------------------------------------
// K5: exact stable top-k order. Composite = (key << 32) | ~idx, rank by
// brute-force comparison (C ~= 1100 candidates). Descending by key, ties by
// ascending index — exactly lax.top_k semantics.
// ---------------------------------------------------------------------------
__global__ __launch_bounds__(1024) void k_rank(const uint2* __restrict__ cand,
                                               const unsigned* __restrict__ ctrl,
                                               unsigned* __restrict__ sel)
{
    int level = blockIdx.x;
    unsigned cnt = ctrl[4 + level];
    if (cnt > CAND_CAP) cnt = CAND_CAP;
    __shared__ unsigned long long a[CAND_CAP];
    for (int i = threadIdx.x; i < (int)cnt; i += 1024) {
        uint2 c = cand[level * CAND_CAP + i];
        a[i] = ((unsigned long long)c.x << 32) | (unsigned)(~c.y);
    }
    __syncthreads();
    for (int i = threadIdx.x; i < (int)cnt; i += 1024) {
        unsigned long long mine = a[i];
        unsigned rank = 0;
        for (int j = 0; j < (int)cnt; ++j) rank += (a[j] > mine) ? 1u : 0u;
        if (rank < TOPKN)
            sel[level * TOPKN + rank] = ~(unsigned)(mine & 0xFFFFFFFFull);
    }
}

// ---------------------------------------------------------------------------
// K6: one block per selected anchor. Gather cls row -> sigmoid in LDS, decode
// both bboxes, emit 80 rows x 12 floats as 240 coalesced float4 stores.
// Row layout: [b0(4), score0, tag, b1(4), score1, tag]
// ---------------------------------------------------------------------------
__global__ __launch_bounds__(256) void k_epilogue(
    const float* a0, const float* a1, const float* a2, const float* a3, const float* a4,
    const float* c0, const float* c1, const float* c2, const float* c3, const float* c4,
    const float* r0, const float* r1, const float* r2, const float* r3, const float* r4,
    const unsigned* __restrict__ sel, float* __restrict__ out)
{
    int s = blockIdx.x;
    int level, idx;
    if (s < 4 * TOPKN) {
        level = s / TOPKN;
        idx   = (int)sel[s];          // sel laid out level*1000 + rank == s
    } else {
        level = 4;
        idx   = s - 4 * TOPKN;
    }
    const float *A, *C, *R;
    switch (level) {
        case 0: A = a0; C = c0; R = r0; break;
        case 1: A = a1; C = c1; R = r1; break;
        case 2: A = a2; C = c2; R = r2; break;
        case 3: A = a3; C = c3; R = r3; break;
        default: A = a4; C = c4; R = r4; break;
    }

    __shared__ float sc[CLS];
    __shared__ float bb[8];

    const float* cp = C + (size_t)idx * CLS;
    if (threadIdx.x < CLS) {
        float x = cp[threadIdx.x];
        sc[threadIdx.x] = 1.0f / (1.0f + __expf(-x));
    }
    if (threadIdx.x == 192) {   // wave 3, not used by the cls gather
        const float* ap = A + (size_t)idx * 4;
        const float* rp = R + (size_t)idx * 8;
        float x1 = ap[0], y1 = ap[1], x2 = ap[2], y2 = ap[3];
        float w  = x2 - x1 + 1.0f, h = y2 - y1 + 1.0f;
        float cx = x1 + 0.5f * w,  cy = y1 + 0.5f * h;
        #pragma unroll
        for (int p = 0; p < 2; ++p) {
            float pcx = cx + rp[4 * p + 0] * w;
            float pcy = cy + rp[4 * p + 1] * h;
            float pw  = w * __expf(rp[4 * p + 2]);
            float ph  = h * __expf(rp[4 * p + 3]);
            bb[4 * p + 0] = pcx - 0.5f * pw;
            bb[4 * p + 1] = pcy - 0.5f * ph;
            bb[4 * p + 2] = pcx + 0.5f * pw;
            bb[4 * p + 3] = pcy + 0.5f * ph;
        }
    }
    __syncthreads();

    float4* orow = (float4*)(out + (size_t)s * 960);   // 80 * 12 floats
    if (threadIdx.x < 240) {
        int j = threadIdx.x / 3, part = threadIdx.x % 3;
        float tag = (float)(j + 1);
        float4 v;
        if (part == 0)      v = make_float4(bb[0], bb[1], bb[2], bb[3]);
        else if (part == 1) v = make_float4(sc[j], tag, bb[4], bb[5]);
        else                v = make_float4(bb[6], bb[7], sc[80 + j], tag);
        orow[threadIdx.x] = v;
    }
}

// ---------------------------------------------------------------------------
// Workspace layout (uint32 words):
//   keys[NROWS] | hist[4*NBINS] | ctrl[8] (thr[4], cnt[4]) |
//   cand[4*CAND_CAP] (uint2)    | sel[4*TOPKN]
// Total ~1.9 MB. Every word consumed is rewritten each call (no memset).
// ---------------------------------------------------------------------------
extern "C" void kernel_launch(void* const* d_in, const int* in_sizes, int n_in,
                              void* d_out, int out_size, void* d_ws, size_t ws_size,
                              hipStream_t stream)
{
    bool interleaved = (in_sizes[1] > 1000000);
    const float *A[5], *C[5], *R[5];
    for (int i = 0; i < 5; ++i) {
        if (interleaved) {
            A[i] = (const float*)d_in[3 * i + 0];
            C[i] = (const float*)d_in[3 * i + 1];
            R[i] = (const float*)d_in[3 * i + 2];
        } else {
            A[i] = (const float*)d_in[i];
            C[i] = (const float*)d_in[5 + i];
            R[i] = (const float*)d_in[10 + i];
        }
    }

    unsigned* keys = (unsigned*)d_ws;
    unsigned* hist = keys + NROWS;
    unsigned* ctrl = hist + 4 * NBINS;
    uint2*    cand = (uint2*)(ctrl + 8);
    unsigned* sel  = (unsigned*)(cand + 4 * CAND_CAP);

    k_ruler<<<1530, 256, 0, stream>>>(C[0], C[1], C[2], C[3], keys);
    k_hist<<<64, 256, 0, stream>>>(keys, hist);
    k_decide<<<4, 1024, 0, stream>>>(hist, ctrl);
    k_compact<<<NROWS / 256, 256, 0, stream>>>(keys, ctrl, cand);
    k_rank<<<4, 1024, 0, stream>>>(cand, ctrl, sel);
    k_epilogue<<<NSEL, 256, 0, stream>>>(A[0], A[1], A[2], A[3], A[4],
                                         C[0], C[1], C[2], C[3], C[4],
                                         R[0], R[1], R[2], R[3], R[4],
                                         sel, (float*)d_out);
}

// Round 4
// 101.075 us; speedup vs baseline: 2.5484x; 2.5484x over previous
//
#include <hip/hip_runtime.h>

#define CLS   160          // CLASS_NUM * NUM_PRED
#define TOPKN 1000
#define N0 147456
#define N1 36864
#define N2 9216
#define N3 2304
#define N4 576
#define NROWS (N0 + N1 + N2 + N3)   // 195840 anchors needing top-k keys
#define BD1 N0
#define BD2 (N0 + N1)
#define BD3 (N0 + N1 + N2)
#define NSEL (4 * TOPKN + N4)       // 4576 selected anchors
#define NBINS 65536
#define CAND_CAP 2048

__device__ __forceinline__ unsigned sortable(float f) {
    unsigned u = __float_as_uint(f);
    return (u & 0x80000000u) ? ~u : (u | 0x80000000u);
}

// ---------------------------------------------------------------------------
// K1: ruler keys, NO atomics. 8 lanes per row, 5 float4 loads per lane.
// Also zeroes hist[4*NBINS] (<=1 word/thread) so no runtime memset kernel
// is needed: the 54us fillBufferAligned dispatch was 39% of R2's runtime.
// ---------------------------------------------------------------------------
__global__ __launch_bounds__(256) void k_ruler(
    const float* __restrict__ c0, const float* __restrict__ c1,
    const float* __restrict__ c2, const float* __restrict__ c3,
    unsigned* __restrict__ keys, unsigned* __restrict__ hist)
{
    int tid  = blockIdx.x * 256 + threadIdx.x;
    if (tid < 4 * NBINS) hist[tid] = 0;   // 262144 words, 391680 threads

    int wv   = tid >> 6;
    int lane = tid & 63;
    int sub  = lane >> 3;   // row within group of 8
    int col  = lane & 7;    // float4 column group
    const int NW = 1530 * 4;
    for (int g = wv; g < NROWS / 8; g += NW) {
        int r0 = g * 8;     // 8 rows, always within one level (sizes % 8 == 0)
        const float* cb; int lr;
        if (r0 < BD1)      { cb = c0; lr = r0; }
        else if (r0 < BD2) { cb = c1; lr = r0 - BD1; }
        else if (r0 < BD3) { cb = c2; lr = r0 - BD2; }
        else               { cb = c3; lr = r0 - BD3; }
        const float4* p = (const float4*)cb + (size_t)(lr + sub) * 40 + col;
        float m = -3.4e38f;
        #pragma unroll
        for (int k = 0; k < 5; ++k) {
            float4 v = p[8 * k];
            m = fmaxf(m, fmaxf(fmaxf(v.x, v.y), fmaxf(v.z, v.w)));
        }
        m = fmaxf(m, __shfl_xor(m, 1));
        m = fmaxf(m, __shfl_xor(m, 2));
        m = fmaxf(m, __shfl_xor(m, 4));
        if (col == 0) keys[r0 + sub] = sortable(m);
    }
}

// ---------------------------------------------------------------------------
// K2: chunked segment histogram. 1024 blocks = (level, 16 segments, 16
// chunks). Each block uint4-scans its chunk (max 9216 keys), LDS-counts its
// segment's bins, flushes only nonzero bins with global atomicAdd into the
// pre-zeroed hist. Hot-segment work is spread over 16 blocks (R3's mistake:
// 1 block scanned a whole level alone -> latency-bound at 0.9% occupancy).
// ---------------------------------------------------------------------------
__global__ __launch_bounds__(256) void k_hist(const unsigned* __restrict__ keys,
                                              unsigned* __restrict__ hist)
{
    int b        = blockIdx.x;       // 1024 blocks
    int level    = b >> 8;
    unsigned seg = (b >> 4) & 15;
    int chunk    = b & 15;
    __shared__ unsigned cnt[4096];
    for (int i = threadIdx.x; i < 4096; i += 256) cnt[i] = 0;
    __syncthreads();
    int base, n;
    switch (level) {
        case 0:  base = 0;   n = N0; break;
        case 1:  base = BD1; n = N1; break;
        case 2:  base = BD2; n = N2; break;
        default: base = BD3; n = N3; break;
    }
    int q = n >> 4;                         // chunk size (all levels % 64 == 0)
    const uint4* kp = (const uint4*)(keys + base + chunk * q);
    int nv = q >> 2;
    for (int i = threadIdx.x; i < nv; i += 256) {
        uint4 k = kp[i];
        unsigned b0 = k.x >> 16, b1 = k.y >> 16, b2 = k.z >> 16, b3 = k.w >> 16;
        if ((b0 >> 12) == seg) atomicAdd(&cnt[b0 & 4095u], 1u);
        if ((b1 >> 12) == seg) atomicAdd(&cnt[b1 & 4095u], 1u);
        if ((b2 >> 12) == seg) atomicAdd(&cnt[b2 & 4095u], 1u);
        if ((b3 >> 12) == seg) atomicAdd(&cnt[b3 & 4095u], 1u);
    }
    __syncthreads();
    unsigned* h = hist + level * NBINS + (seg << 12);
    for (int i = threadIdx.x; i < 4096; i += 256) {
        unsigned c = cnt[i];
        if (c) atomicAdd(&h[i], c);
    }
}

// ---------------------------------------------------------------------------
// K3: per level (4 blocks), scan histogram descending to find the bin holding
// the 1000th-largest key. Threshold = lower edge of that bin. Also zero the
// candidate counter for this call.
// ---------------------------------------------------------------------------
__global__ __launch_bounds__(1024) void k_decide(const unsigned* __restrict__ hist,
                                                 unsigned* __restrict__ ctrl)
{
    int level = blockIdx.x;
    const unsigned* h = hist + level * NBINS;
    int t = threadIdx.x;
    __shared__ unsigned s[1024];

    unsigned sum = 0;
    #pragma unroll 4
    for (int i = 0; i < 64; ++i) sum += h[t * 64 + i];
    s[t] = sum;
    __syncthreads();

    // suffix sums: s[t] = sum over chunks t..1023 (Hillis-Steele)
    for (int off = 1; off < 1024; off <<= 1) {
        unsigned v   = s[t];
        unsigned add = (t + off < 1024) ? s[t + off] : 0u;
        __syncthreads();
        s[t] = v + add;
        __syncthreads();
    }

    // exactly one thread has suf[t] >= K and suf[t+1] < K (suf nonincreasing)
    if (s[t] >= TOPKN && (t == 1023 || s[t + 1] < TOPKN)) {
        unsigned cum = (t == 1023) ? 0u : s[t + 1];
        int edge = t * 64;
        for (int b = t * 64 + 63; b >= t * 64; --b) {
            cum += h[b];
            if (cum >= TOPKN) { edge = b; break; }
        }
        ctrl[level]     = ((unsigned)edge) << 16;  // threshold key
        ctrl[4 + level] = 0u;                      // reset candidate counter
    }
}

// ---------------------------------------------------------------------------
// K4: compact (key, local_idx) with key >= threshold. Wave-aggregated
// counter atomic: one atomicAdd per wave with >=1 candidate. Level
// boundaries are all multiples of 64, so a wave never straddles levels.
// ---------------------------------------------------------------------------
__global__ __launch_bounds__(256) void k_compact(const unsigned* __restrict__ keys,
                                                 unsigned* __restrict__ ctrl,
                                                 uint2* __restrict__ cand)
{
    int w = blockIdx.x * 256 + threadIdx.x;
    int lane = threadIdx.x & 63;
    int level, base;
    if (w < BD1)      { level = 0; base = 0;   }
    else if (w < BD2) { level = 1; base = BD1; }
    else if (w < BD3) { level = 2; base = BD2; }
    else              { level = 3; base = BD3; }
    unsigned key = keys[w];
    bool pass = key >= ctrl[level];
    unsigned long long mask = __ballot(pass);
    if (pass) {
        int leader    = __ffsll((long long)mask) - 1;
        unsigned tot  = (unsigned)__popcll(mask);
        unsigned rank = (unsigned)__popcll(mask & ((1ull << lane) - 1ull));
        unsigned bpos = 0;
        if (lane == leader) bpos = atomicAdd(&ctrl[4 + level], tot);
        bpos = (unsigned)__shfl((int)bpos, leader);
        unsigned pos = bpos + rank;
        if (pos < CAND_CAP)
            cand[level * CAND_CAP + pos] = make_uint2(key, (unsigned)(w - base));
    }
}

// ---------------------------------------------------------------------------
// K5: exact stable top-k order. Composite = (key << 32) | ~idx, rank by
// brute-force comparison (C ~= 1100 candidates). Descending by key, ties by
// ascending index — exactly lax.top_k semantics.
// ---------------------------------------------------------------------------
__global__ __launch_bounds__(1024) void k_rank(const uint2* __restrict__ cand,
                                               const unsigned* __restrict__ ctrl,
                                               unsigned* __restrict__ sel)
{
    int level = blockIdx.x;
    unsigned cnt = ctrl[4 + level];
    if (cnt > CAND_CAP) cnt = CAND_CAP;
    __shared__ unsigned long long a[CAND_CAP];
    for (int i = threadIdx.x; i < (int)cnt; i += 1024) {
        uint2 c = cand[level * CAND_CAP + i];
        a[i] = ((unsigned long long)c.x << 32) | (unsigned)(~c.y);
    }
    __syncthreads();
    for (int i = threadIdx.x; i < (int)cnt; i += 1024) {
        unsigned long long mine = a[i];
        unsigned rank = 0;
        for (int j = 0; j < (int)cnt; ++j) rank += (a[j] > mine) ? 1u : 0u;
        if (rank < TOPKN)
            sel[level * TOPKN + rank] = ~(unsigned)(mine & 0xFFFFFFFFull);
    }
}

// ---------------------------------------------------------------------------
// K6: one block per selected anchor. Gather cls row -> sigmoid in LDS, decode
// both bboxes, emit 80 rows x 12 floats as 240 coalesced float4 stores.
// Row layout: [b0(4), score0, tag, b1(4), score1, tag]
// ---------------------------------------------------------------------------
__global__ __launch_bounds__(256) void k_epilogue(
    const float* a0, const float* a1, const float* a2, const float* a3, const float* a4,
    const float* c0, const float* c1, const float* c2, const float* c3, const float* c4,
    const float* r0, const float* r1, const float* r2, const float* r3, const float* r4,
    const unsigned* __restrict__ sel, float* __restrict__ out)
{
    int s = blockIdx.x;
    int level, idx;
    if (s < 4 * TOPKN) {
        level = s / TOPKN;
        idx   = (int)sel[s];          // sel laid out level*1000 + rank == s
    } else {
        level = 4;
        idx   = s - 4 * TOPKN;
    }
    const float *A, *C, *R;
    switch (level) {
        case 0: A = a0; C = c0; R = r0; break;
        case 1: A = a1; C = c1; R = r1; break;
        case 2: A = a2; C = c2; R = r2; break;
        case 3: A = a3; C = c3; R = r3; break;
        default: A = a4; C = c4; R = r4; break;
    }

    __shared__ float sc[CLS];
    __shared__ float bb[8];

    const float* cp = C + (size_t)idx * CLS;
    if (threadIdx.x < CLS) {
        float x = cp[threadIdx.x];
        sc[threadIdx.x] = 1.0f / (1.0f + __expf(-x));
    }
    if (threadIdx.x == 192) {   // wave 3, not used by the cls gather
        const float* ap = A + (size_t)idx * 4;
        const float* rp = R + (size_t)idx * 8;
        float x1 = ap[0], y1 = ap[1], x2 = ap[2], y2 = ap[3];
        float w  = x2 - x1 + 1.0f, h = y2 - y1 + 1.0f;
        float cx = x1 + 0.5f * w,  cy = y1 + 0.5f * h;
        #pragma unroll
        for (int p = 0; p < 2; ++p) {
            float pcx = cx + rp[4 * p + 0] * w;
            float pcy = cy + rp[4 * p + 1] * h;
            float pw  = w * __expf(rp[4 * p + 2]);
            float ph  = h * __expf(rp[4 * p + 3]);
            bb[4 * p + 0] = pcx - 0.5f * pw;
            bb[4 * p + 1] = pcy - 0.5f * ph;
            bb[4 * p + 2] = pcx + 0.5f * pw;
            bb[4 * p + 3] = pcy + 0.5f * ph;
        }
    }
    __syncthreads();

    float4* orow = (float4*)(out + (size_t)s * 960);   // 80 * 12 floats
    if (threadIdx.x < 240) {
        int j = threadIdx.x / 3, part = threadIdx.x % 3;
        float tag = (float)(j + 1);
        float4 v;
        if (part == 0)      v = make_float4(bb[0], bb[1], bb[2], bb[3]);
        else if (part == 1) v = make_float4(sc[j], tag, bb[4], bb[5]);
        else                v = make_float4(bb[6], bb[7], sc[80 + j], tag);
        orow[threadIdx.x] = v;
    }
}

// ---------------------------------------------------------------------------
// Workspace layout (uint32 words):
//   keys[NROWS] | hist[4*NBINS] | ctrl[8] (thr[4], cnt[4]) |
//   cand[4*CAND_CAP] (uint2)    | sel[4*TOPKN]
// Total ~1.9 MB. hist is zeroed by k_ruler each call (no memset kernel).
// ---------------------------------------------------------------------------
extern "C" void kernel_launch(void* const* d_in, const int* in_sizes, int n_in,
                              void* d_out, int out_size, void* d_ws, size_t ws_size,
                              hipStream_t stream)
{
    bool interleaved = (in_sizes[1] > 1000000);
    const float *A[5], *C[5], *R[5];
    for (int i = 0; i < 5; ++i) {
        if (interleaved) {
            A[i] = (const float*)d_in[3 * i + 0];
            C[i] = (const float*)d_in[3 * i + 1];
            R[i] = (const float*)d_in[3 * i + 2];
        } else {
            A[i] = (const float*)d_in[i];
            C[i] = (const float*)d_in[5 + i];
            R[i] = (const float*)d_in[10 + i];
        }
    }

    unsigned* keys = (unsigned*)d_ws;
    unsigned* hist = keys + NROWS;
    unsigned* ctrl = hist + 4 * NBINS;
    uint2*    cand = (uint2*)(ctrl + 8);
    unsigned* sel  = (unsigned*)(cand + 4 * CAND_CAP);

    k_ruler<<<1530, 256, 0, stream>>>(C[0], C[1], C[2], C[3], keys, hist);
    k_hist<<<1024, 256, 0, stream>>>(keys, hist);
    k_decide<<<4, 1024, 0, stream>>>(hist, ctrl);
    k_compact<<<NROWS / 256, 256, 0, stream>>>(keys, ctrl, cand);
    k_rank<<<4, 1024, 0, stream>>>(cand, ctrl, sel);
    k_epilogue<<<NSEL, 256, 0, stream>>>(A[0], A[1], A[2], A[3], A[4],
                                         C[0], C[1], C[2], C[3], C[4],
                                         R[0], R[1], R[2], R[3], R[4],
                                         sel, (float*)d_out);
}

// Round 5
// 89.447 us; speedup vs baseline: 2.8797x; 1.1300x over previous
//
#include <hip/hip_runtime.h>

#define CLS   160          // CLASS_NUM * NUM_PRED
#define TOPKN 1000
#define N0 147456
#define N1 36864
#define N2 9216
#define N3 2304
#define N4 576
#define NROWS (N0 + N1 + N2 + N3)   // 195840 anchors needing top-k keys
#define BD1 N0
#define BD2 (N0 + N1)
#define BD3 (N0 + N1 + N2)
#define NSEL (4 * TOPKN + N4)       // 4576 selected anchors
#define NBINS 65536
#define CAND_CAP 2048

__device__ __forceinline__ unsigned sortable(float f) {
    unsigned u = __float_as_uint(f);
    return (u & 0x80000000u) ? ~u : (u | 0x80000000u);
}

// ---------------------------------------------------------------------------
// K1: ruler keys, NO atomics. Static mapping: block b owns rows
// [b*128, b*128+128) — always within one level (all level sizes % 128 == 0;
// 1530 blocks exactly). 8 lanes per row, 5 float4 loads per lane, 3-step
// shuffle reduce. Also zeroes hist[4*NBINS] (<=1 word/thread): the 54us
// fillBufferAligned dispatch was 39% of R2's runtime.
// ---------------------------------------------------------------------------
__global__ __launch_bounds__(256) void k_ruler(
    const float* __restrict__ c0, const float* __restrict__ c1,
    const float* __restrict__ c2, const float* __restrict__ c3,
    unsigned* __restrict__ keys, unsigned* __restrict__ hist)
{
    int tid = blockIdx.x * 256 + threadIdx.x;
    if (tid < 4 * NBINS) hist[tid] = 0;   // 262144 words, 391680 threads

    int r0 = blockIdx.x << 7;             // first global row of this block
    const float* cb; int lr0;
    if (r0 < BD1)      { cb = c0; lr0 = r0; }
    else if (r0 < BD2) { cb = c1; lr0 = r0 - BD1; }
    else if (r0 < BD3) { cb = c2; lr0 = r0 - BD2; }
    else               { cb = c3; lr0 = r0 - BD3; }

    int wv   = threadIdx.x >> 6;
    int lane = threadIdx.x & 63;
    int sub  = lane >> 3;   // row within group of 8
    int col  = lane & 7;    // float4 column group
    #pragma unroll
    for (int i = 0; i < 4; ++i) {
        int rrel = wv * 32 + i * 8 + sub;
        const float4* p = (const float4*)cb + (size_t)(lr0 + rrel) * 40 + col;
        float m = -3.4e38f;
        #pragma unroll
        for (int k = 0; k < 5; ++k) {
            float4 v = p[8 * k];
            m = fmaxf(m, fmaxf(fmaxf(v.x, v.y), fmaxf(v.z, v.w)));
        }
        m = fmaxf(m, __shfl_xor(m, 1));
        m = fmaxf(m, __shfl_xor(m, 2));
        m = fmaxf(m, __shfl_xor(m, 4));
        if (col == 0) keys[r0 + rrel] = sortable(m);
    }
}

// ---------------------------------------------------------------------------
// K2: chunked segment histogram. 1024 blocks = (level, 16 segments, 16
// chunks). Each block uint4-scans its chunk (max 9216 keys), LDS-counts its
// segment's bins, flushes only nonzero bins with global atomicAdd into the
// pre-zeroed hist.
// ---------------------------------------------------------------------------
__global__ __launch_bounds__(256) void k_hist(const unsigned* __restrict__ keys,
                                              unsigned* __restrict__ hist)
{
    int b        = blockIdx.x;       // 1024 blocks
    int level    = b >> 8;
    unsigned seg = (b >> 4) & 15;
    int chunk    = b & 15;
    __shared__ unsigned cnt[4096];
    for (int i = threadIdx.x; i < 4096; i += 256) cnt[i] = 0;
    __syncthreads();
    int base, n;
    switch (level) {
        case 0:  base = 0;   n = N0; break;
        case 1:  base = BD1; n = N1; break;
        case 2:  base = BD2; n = N2; break;
        default: base = BD3; n = N3; break;
    }
    int q = n >> 4;                         // chunk size (all levels % 64 == 0)
    const uint4* kp = (const uint4*)(keys + base + chunk * q);
    int nv = q >> 2;
    for (int i = threadIdx.x; i < nv; i += 256) {
        uint4 k = kp[i];
        unsigned b0 = k.x >> 16, b1 = k.y >> 16, b2 = k.z >> 16, b3 = k.w >> 16;
        if ((b0 >> 12) == seg) atomicAdd(&cnt[b0 & 4095u], 1u);
        if ((b1 >> 12) == seg) atomicAdd(&cnt[b1 & 4095u], 1u);
        if ((b2 >> 12) == seg) atomicAdd(&cnt[b2 & 4095u], 1u);
        if ((b3 >> 12) == seg) atomicAdd(&cnt[b3 & 4095u], 1u);
    }
    __syncthreads();
    unsigned* h = hist + level * NBINS + (seg << 12);
    for (int i = threadIdx.x; i < 4096; i += 256) {
        unsigned c = cnt[i];
        if (c) atomicAdd(&h[i], c);
    }
}

// ---------------------------------------------------------------------------
// K3: fused decide+compact+rank, one block per level (4 x 1024). Replaces
// three kernels and the global ctrl/cand round-trips (2 graph nodes saved).
//  A: scan hist descending -> threshold bin lower edge (in LDS).
//  B: uint4-scan level keys; passing keys appended to LDS composite array
//     via wave-aggregated ballot (one LDS atomic per wave per component).
//  C: brute-force exact rank (descending key, ties ascending index — exact
//     lax.top_k semantics); write sel[level*1000+rank].
// ---------------------------------------------------------------------------
__global__ __launch_bounds__(1024) void k_select(const unsigned* __restrict__ keys,
                                                 const unsigned* __restrict__ hist,
                                                 unsigned* __restrict__ sel)
{
    int level = blockIdx.x;
    int t     = threadIdx.x;
    int lane  = t & 63;
    const unsigned* h = hist + level * NBINS;

    __shared__ unsigned s[1024];
    __shared__ unsigned long long a[CAND_CAP];
    __shared__ unsigned thr_s, cnt_s;

    // ---- A: decide threshold ----
    unsigned sum = 0;
    #pragma unroll 4
    for (int i = 0; i < 64; ++i) sum += h[t * 64 + i];
    s[t] = sum;
    if (t == 0) cnt_s = 0;
    __syncthreads();
    for (int off = 1; off < 1024; off <<= 1) {   // suffix sums
        unsigned v   = s[t];
        unsigned add = (t + off < 1024) ? s[t + off] : 0u;
        __syncthreads();
        s[t] = v + add;
        __syncthreads();
    }
    if (s[t] >= TOPKN && (t == 1023 || s[t + 1] < TOPKN)) {
        unsigned cum = (t == 1023) ? 0u : s[t + 1];
        int edge = t * 64;
        for (int b = t * 64 + 63; b >= t * 64; --b) {
            cum += h[b];
            if (cum >= TOPKN) { edge = b; break; }
        }
        thr_s = ((unsigned)edge) << 16;
    }
    __syncthreads();
    unsigned thr = thr_s;

    // ---- B: compact into LDS (wave-aggregated append) ----
    int base, n;
    switch (level) {
        case 0:  base = 0;   n = N0; break;
        case 1:  base = BD1; n = N1; break;
        case 2:  base = BD2; n = N2; break;
        default: base = BD3; n = N3; break;
    }
    const uint4* kp = (const uint4*)(keys + base);
    int nv = n >> 2;
    for (int i = t; i < nv; i += 1024) {
        uint4 k4 = kp[i];
        unsigned kv[4] = {k4.x, k4.y, k4.z, k4.w};
        #pragma unroll
        for (int c = 0; c < 4; ++c) {
            bool pass = kv[c] >= thr;
            unsigned long long mask = __ballot(pass);
            if (pass) {
                int leader    = __ffsll((long long)mask) - 1;
                unsigned tot  = (unsigned)__popcll(mask);
                unsigned rank = (unsigned)__popcll(mask & ((1ull << lane) - 1ull));
                unsigned bp = 0;
                if (lane == leader) bp = atomicAdd(&cnt_s, tot);
                bp = (unsigned)__shfl((int)bp, leader);
                unsigned pos = bp + rank;
                if (pos < CAND_CAP)
                    a[pos] = ((unsigned long long)kv[c] << 32) |
                             (unsigned)~(unsigned)(4 * i + c);
            }
        }
    }
    __syncthreads();
    unsigned cnt = cnt_s;
    if (cnt > CAND_CAP) cnt = CAND_CAP;

    // ---- C: exact rank ----
    for (int i = t; i < (int)cnt; i += 1024) {
        unsigned long long mine = a[i];
        unsigned rank = 0;
        for (int j = 0; j < (int)cnt; ++j) rank += (a[j] > mine) ? 1u : 0u;
        if (rank < TOPKN)
            sel[level * TOPKN + rank] = ~(unsigned)(mine & 0xFFFFFFFFull);
    }
}

// ---------------------------------------------------------------------------
// K4: one block per selected anchor. Gather cls row -> sigmoid in LDS, decode
// both bboxes, emit 80 rows x 12 floats as 240 coalesced float4 stores.
// Row layout: [b0(4), score0, tag, b1(4), score1, tag]
// ---------------------------------------------------------------------------
__global__ __launch_bounds__(256) void k_epilogue(
    const float* a0, const float* a1, const float* a2, const float* a3, const float* a4,
    const float* c0, const float* c1, const float* c2, const float* c3, const float* c4,
    const float* r0, const float* r1, const float* r2, const float* r3, const float* r4,
    const unsigned* __restrict__ sel, float* __restrict__ out)
{
    int s = blockIdx.x;
    int level, idx;
    if (s < 4 * TOPKN) {
        level = s / TOPKN;
        idx   = (int)sel[s];          // sel laid out level*1000 + rank == s
    } else {
        level = 4;
        idx   = s - 4 * TOPKN;
    }
    const float *A, *C, *R;
    switch (level) {
        case 0: A = a0; C = c0; R = r0; break;
        case 1: A = a1; C = c1; R = r1; break;
        case 2: A = a2; C = c2; R = r2; break;
        case 3: A = a3; C = c3; R = r3; break;
        default: A = a4; C = c4; R = r4; break;
    }

    __shared__ float sc[CLS];
    __shared__ float bb[8];

    const float* cp = C + (size_t)idx * CLS;
    if (threadIdx.x < CLS) {
        float x = cp[threadIdx.x];
        sc[threadIdx.x] = 1.0f / (1.0f + __expf(-x));
    }
    if (threadIdx.x == 192) {   // wave 3, not used by the cls gather
        const float* ap = A + (size_t)idx * 4;
        const float* rp = R + (size_t)idx * 8;
        float x1 = ap[0], y1 = ap[1], x2 = ap[2], y2 = ap[3];
        float w  = x2 - x1 + 1.0f, h = y2 - y1 + 1.0f;
        float cx = x1 + 0.5f * w,  cy = y1 + 0.5f * h;
        #pragma unroll
        for (int p = 0; p < 2; ++p) {
            float pcx = cx + rp[4 * p + 0] * w;
            float pcy = cy + rp[4 * p + 1] * h;
            float pw  = w * __expf(rp[4 * p + 2]);
            float ph  = h * __expf(rp[4 * p + 3]);
            bb[4 * p + 0] = pcx - 0.5f * pw;
            bb[4 * p + 1] = pcy - 0.5f * ph;
            bb[4 * p + 2] = pcx + 0.5f * pw;
            bb[4 * p + 3] = pcy + 0.5f * ph;
        }
    }
    __syncthreads();

    float4* orow = (float4*)(out + (size_t)s * 960);   // 80 * 12 floats
    if (threadIdx.x < 240) {
        int j = threadIdx.x / 3, part = threadIdx.x % 3;
        float tag = (float)(j + 1);
        float4 v;
        if (part == 0)      v = make_float4(bb[0], bb[1], bb[2], bb[3]);
        else if (part == 1) v = make_float4(sc[j], tag, bb[4], bb[5]);
        else                v = make_float4(bb[6], bb[7], sc[80 + j], tag);
        orow[threadIdx.x] = v;
    }
}

// ---------------------------------------------------------------------------
// Workspace layout (uint32 words):
//   keys[NROWS] | hist[4*NBINS] | sel[4*TOPKN]     (~1.8 MB)
// hist is zeroed by k_ruler each call (no memset kernel, no ctrl/cand).
// ---------------------------------------------------------------------------
extern "C" void kernel_launch(void* const* d_in, const int* in_sizes, int n_in,
                              void* d_out, int out_size, void* d_ws, size_t ws_size,
                              hipStream_t stream)
{
    bool interleaved = (in_sizes[1] > 1000000);
    const float *A[5], *C[5], *R[5];
    for (int i = 0; i < 5; ++i) {
        if (interleaved) {
            A[i] = (const float*)d_in[3 * i + 0];
            C[i] = (const float*)d_in[3 * i + 1];
            R[i] = (const float*)d_in[3 * i + 2];
        } else {
            A[i] = (const float*)d_in[i];
            C[i] = (const float*)d_in[5 + i];
            R[i] = (const float*)d_in[10 + i];
        }
    }

    unsigned* keys = (unsigned*)d_ws;
    unsigned* hist = keys + NROWS;
    unsigned* sel  = hist + 4 * NBINS;

    k_ruler<<<1530, 256, 0, stream>>>(C[0], C[1], C[2], C[3], keys, hist);
    k_hist<<<1024, 256, 0, stream>>>(keys, hist);
    k_select<<<4, 1024, 0, stream>>>(keys, hist, sel);
    k_epilogue<<<NSEL, 256, 0, stream>>>(A[0], A[1], A[2], A[3], A[4],
                                         C[0], C[1], C[2], C[3], C[4],
                                         R[0], R[1], R[2], R[3], R[4],
                                         sel, (float*)d_out);
}

// Round 6
// 82.413 us; speedup vs baseline: 3.1255x; 1.0854x over previous
//
#include <hip/hip_runtime.h>

#define CLS   160          // CLASS_NUM * NUM_PRED
#define TOPKN 1000
#define N0 147456
#define N1 36864
#define N2 9216
#define N3 2304
#define N4 576
#define NROWS (N0 + N1 + N2 + N3)   // 195840 anchors needing top-k keys
#define BD1 N0
#define BD2 (N0 + N1)
#define BD3 (N0 + N1 + N2)
#define NSEL (4 * TOPKN + N4)       // 4576 selected anchors
#define NBINS 65536
#define CAND_CAP 2048

__device__ __forceinline__ unsigned sortable(float f) {
    unsigned u = __float_as_uint(f);
    return (u & 0x80000000u) ? ~u : (u | 0x80000000u);
}

// ---------------------------------------------------------------------------
// K1: ruler keys, NO atomics. Static mapping: block b owns rows
// [b*128, b*128+128) — always within one level. 8 lanes per row, 5 float4
// loads per lane, 3-step shuffle reduce. Also zeroes hist (262144 w) and
// coarse (4096 w) so no runtime memset kernel is needed.
// ---------------------------------------------------------------------------
__global__ __launch_bounds__(256) void k_ruler(
    const float* __restrict__ c0, const float* __restrict__ c1,
    const float* __restrict__ c2, const float* __restrict__ c3,
    unsigned* __restrict__ keys, unsigned* __restrict__ hist)
{
    int tid = blockIdx.x * 256 + threadIdx.x;
    if (tid < 4 * NBINS + 4096) hist[tid] = 0;   // hist + adjacent coarse

    int r0 = blockIdx.x << 7;             // first global row of this block
    const float* cb; int lr0;
    if (r0 < BD1)      { cb = c0; lr0 = r0; }
    else if (r0 < BD2) { cb = c1; lr0 = r0 - BD1; }
    else if (r0 < BD3) { cb = c2; lr0 = r0 - BD2; }
    else               { cb = c3; lr0 = r0 - BD3; }

    int wv   = threadIdx.x >> 6;
    int lane = threadIdx.x & 63;
    int sub  = lane >> 3;   // row within group of 8
    int col  = lane & 7;    // float4 column group
    #pragma unroll
    for (int i = 0; i < 4; ++i) {
        int rrel = wv * 32 + i * 8 + sub;
        const float4* p = (const float4*)cb + (size_t)(lr0 + rrel) * 40 + col;
        float m = -3.4e38f;
        #pragma unroll
        for (int k = 0; k < 5; ++k) {
            float4 v = p[8 * k];
            m = fmaxf(m, fmaxf(fmaxf(v.x, v.y), fmaxf(v.z, v.w)));
        }
        m = fmaxf(m, __shfl_xor(m, 1));
        m = fmaxf(m, __shfl_xor(m, 2));
        m = fmaxf(m, __shfl_xor(m, 4));
        if (col == 0) keys[r0 + rrel] = sortable(m);
    }
}

// ---------------------------------------------------------------------------
// K2: chunked segment histogram. 1024 blocks = (level, 16 segments, 16
// chunks). LDS-counts its segment's bins, flushes nonzero bins (atomicAdd
// into pre-zeroed hist) AND per-64-bin-chunk sums into coarse[level][1024]
// (XOR-rotated LDS reads: 2 lanes/bank = conflict-free). coarse makes
// k_select's threshold search O(1) transactions instead of a 64K-word
// uncoalesced scan (R5: 60us at 0.4% VALUBusy on one CU per level).
// ---------------------------------------------------------------------------
__global__ __launch_bounds__(256) void k_hist(const unsigned* __restrict__ keys,
                                              unsigned* __restrict__ hist,
                                              unsigned* __restrict__ coarse)
{
    int b        = blockIdx.x;       // 1024 blocks
    int level    = b >> 8;
    unsigned seg = (b >> 4) & 15;
    int chunk    = b & 15;
    __shared__ unsigned cnt[4096];
    for (int i = threadIdx.x; i < 4096; i += 256) cnt[i] = 0;
    __syncthreads();
    int base, n;
    switch (level) {
        case 0:  base = 0;   n = N0; break;
        case 1:  base = BD1; n = N1; break;
        case 2:  base = BD2; n = N2; break;
        default: base = BD3; n = N3; break;
    }
    int q = n >> 4;                         // chunk size
    const uint4* kp = (const uint4*)(keys + base + chunk * q);
    int nv = q >> 2;
    for (int i = threadIdx.x; i < nv; i += 256) {
        uint4 k = kp[i];
        unsigned b0 = k.x >> 16, b1 = k.y >> 16, b2 = k.z >> 16, b3 = k.w >> 16;
        if ((b0 >> 12) == seg) atomicAdd(&cnt[b0 & 4095u], 1u);
        if ((b1 >> 12) == seg) atomicAdd(&cnt[b1 & 4095u], 1u);
        if ((b2 >> 12) == seg) atomicAdd(&cnt[b2 & 4095u], 1u);
        if ((b3 >> 12) == seg) atomicAdd(&cnt[b3 & 4095u], 1u);
    }
    __syncthreads();
    unsigned* h = hist + level * NBINS + (seg << 12);
    for (int i = threadIdx.x; i < 4096; i += 256) {
        unsigned c = cnt[i];
        if (c) atomicAdd(&h[i], c);
    }
    // per-chunk (64-bin) sums -> coarse
    if (threadIdx.x < 64) {
        int j = threadIdx.x;
        unsigned s2 = 0;
        #pragma unroll 8
        for (int i = 0; i < 64; ++i) s2 += cnt[j * 64 + ((i + j) & 63)];
        if (s2) atomicAdd(&coarse[level * 1024 + (int)(seg << 6) + j], s2);
    }
}

// ---------------------------------------------------------------------------
// K3: fused decide+compact+rank, one block per level (4 x 1024).
//  A: coalesced coarse[1024] load -> LDS suffix scan -> edge chunk; wave 0
//     refines inside the chunk with ONE coalesced hist load + shuffle
//     suffix-sum + ballot (no dependent-load scan).
//  B: uint4-scan level keys; passing keys appended to LDS composite array
//     via wave-aggregated ballot.
//  C: brute-force exact rank (descending key, ties ascending index — exact
//     lax.top_k semantics); write sel[level*1000+rank].
// ---------------------------------------------------------------------------
__global__ __launch_bounds__(1024) void k_select(const unsigned* __restrict__ keys,
                                                 const unsigned* __restrict__ hist,
                                                 const unsigned* __restrict__ coarse,
                                                 unsigned* __restrict__ sel)
{
    int level = blockIdx.x;
    int t     = threadIdx.x;
    int lane  = t & 63;
    const unsigned* h = hist + level * NBINS;

    __shared__ unsigned s[1024];
    __shared__ unsigned long long a[CAND_CAP];
    __shared__ unsigned thr_s, cnt_s, chunk_s, cum0_s;

    // ---- A: decide threshold ----
    s[t] = coarse[level * 1024 + t];          // one coalesced load
    if (t == 0) cnt_s = 0;
    __syncthreads();
    for (int off = 1; off < 1024; off <<= 1) {   // suffix sums
        unsigned v   = s[t];
        unsigned add = (t + off < 1024) ? s[t + off] : 0u;
        __syncthreads();
        s[t] = v + add;
        __syncthreads();
    }
    if (s[t] >= TOPKN && (t == 1023 || s[t + 1] < TOPKN)) {
        chunk_s = (unsigned)t;
        cum0_s  = (t == 1023) ? 0u : s[t + 1];
    }
    __syncthreads();
    if (t < 64) {
        unsigned c = h[chunk_s * 64 + (unsigned)t];     // coalesced 256B
        unsigned suf = c;                                // inclusive suffix sum
        #pragma unroll
        for (int off = 1; off < 64; off <<= 1) {
            unsigned v = __shfl_down(suf, off);
            if (t + off < 64) suf += v;
        }
        unsigned long long mask = __ballot(cum0_s + suf >= TOPKN);
        if (t == 0)
            thr_s = (chunk_s * 64 + (63 - (unsigned)__clzll(mask))) << 16;
    }
    __syncthreads();
    unsigned thr = thr_s;

    // ---- B: compact into LDS (wave-aggregated append) ----
    int base, n;
    switch (level) {
        case 0:  base = 0;   n = N0; break;
        case 1:  base = BD1; n = N1; break;
        case 2:  base = BD2; n = N2; break;
        default: base = BD3; n = N3; break;
    }
    const uint4* kp = (const uint4*)(keys + base);
    int nv = n >> 2;
    for (int i = t; i < nv; i += 1024) {
        uint4 k4 = kp[i];
        unsigned kv[4] = {k4.x, k4.y, k4.z, k4.w};
        #pragma unroll
        for (int c = 0; c < 4; ++c) {
            bool pass = kv[c] >= thr;
            unsigned long long mask = __ballot(pass);
            if (pass) {
                int leader    = __ffsll((long long)mask) - 1;
                unsigned tot  = (unsigned)__popcll(mask);
                unsigned rank = (unsigned)__popcll(mask & ((1ull << lane) - 1ull));
                unsigned bp = 0;
                if (lane == leader) bp = atomicAdd(&cnt_s, tot);
                bp = (unsigned)__shfl((int)bp, leader);
                unsigned pos = bp + rank;
                if (pos < CAND_CAP)
                    a[pos] = ((unsigned long long)kv[c] << 32) |
                             (unsigned)~(unsigned)(4 * i + c);
            }
        }
    }
    __syncthreads();
    unsigned cnt = cnt_s;
    if (cnt > CAND_CAP) cnt = CAND_CAP;

    // ---- C: exact rank ----
    for (int i = t; i < (int)cnt; i += 1024) {
        unsigned long long mine = a[i];
        unsigned rank = 0;
        for (int j = 0; j < (int)cnt; ++j) rank += (a[j] > mine) ? 1u : 0u;
        if (rank < TOPKN)
            sel[level * TOPKN + rank] = ~(unsigned)(mine & 0xFFFFFFFFull);
    }
}

// ---------------------------------------------------------------------------
// K4: one block per selected anchor. Gather cls row -> sigmoid in LDS, decode
// both bboxes, emit 80 rows x 12 floats as 240 coalesced float4 stores.
// Row layout: [b0(4), score0, tag, b1(4), score1, tag]
// ---------------------------------------------------------------------------
__global__ __launch_bounds__(256) void k_epilogue(
    const float* a0, const float* a1, const float* a2, const float* a3, const float* a4,
    const float* c0, const float* c1, const float* c2, const float* c3, const float* c4,
    const float* r0, const float* r1, const float* r2, const float* r3, const float* r4,
    const unsigned* __restrict__ sel, float* __restrict__ out)
{
    int s = blockIdx.x;
    int level, idx;
    if (s < 4 * TOPKN) {
        level = s / TOPKN;
        idx   = (int)sel[s];          // sel laid out level*1000 + rank == s
    } else {
        level = 4;
        idx   = s - 4 * TOPKN;
    }
    const float *A, *C, *R;
    switch (level) {
        case 0: A = a0; C = c0; R = r0; break;
        case 1: A = a1; C = c1; R = r1; break;
        case 2: A = a2; C = c2; R = r2; break;
        case 3: A = a3; C = c3; R = r3; break;
        default: A = a4; C = c4; R = r4; break;
    }

    __shared__ float sc[CLS];
    __shared__ float bb[8];

    const float* cp = C + (size_t)idx * CLS;
    if (threadIdx.x < CLS) {
        float x = cp[threadIdx.x];
        sc[threadIdx.x] = 1.0f / (1.0f + __expf(-x));
    }
    if (threadIdx.x == 192) {   // wave 3, not used by the cls gather
        const float* ap = A + (size_t)idx * 4;
        const float* rp = R + (size_t)idx * 8;
        float x1 = ap[0], y1 = ap[1], x2 = ap[2], y2 = ap[3];
        float w  = x2 - x1 + 1.0f, h = y2 - y1 + 1.0f;
        float cx = x1 + 0.5f * w,  cy = y1 + 0.5f * h;
        #pragma unroll
        for (int p = 0; p < 2; ++p) {
            float pcx = cx + rp[4 * p + 0] * w;
            float pcy = cy + rp[4 * p + 1] * h;
            float pw  = w * __expf(rp[4 * p + 2]);
            float ph  = h * __expf(rp[4 * p + 3]);
            bb[4 * p + 0] = pcx - 0.5f * pw;
            bb[4 * p + 1] = pcy - 0.5f * ph;
            bb[4 * p + 2] = pcx + 0.5f * pw;
            bb[4 * p + 3] = pcy + 0.5f * ph;
        }
    }
    __syncthreads();

    float4* orow = (float4*)(out + (size_t)s * 960);   // 80 * 12 floats
    if (threadIdx.x < 240) {
        int j = threadIdx.x / 3, part = threadIdx.x % 3;
        float tag = (float)(j + 1);
        float4 v;
        if (part == 0)      v = make_float4(bb[0], bb[1], bb[2], bb[3]);
        else if (part == 1) v = make_float4(sc[j], tag, bb[4], bb[5]);
        else                v = make_float4(bb[6], bb[7], sc[80 + j], tag);
        orow[threadIdx.x] = v;
    }
}

// ---------------------------------------------------------------------------
// Workspace layout (uint32 words):
//   keys[NROWS] | hist[4*NBINS] | coarse[4*1024] | sel[4*TOPKN]   (~1.8 MB)
// hist+coarse are zeroed by k_ruler each call (no memset kernel).
// ---------------------------------------------------------------------------
extern "C" void kernel_launch(void* const* d_in, const int* in_sizes, int n_in,
                              void* d_out, int out_size, void* d_ws, size_t ws_size,
                              hipStream_t stream)
{
    bool interleaved = (in_sizes[1] > 1000000);
    const float *A[5], *C[5], *R[5];
    for (int i = 0; i < 5; ++i) {
        if (interleaved) {
            A[i] = (const float*)d_in[3 * i + 0];
            C[i] = (const float*)d_in[3 * i + 1];
            R[i] = (const float*)d_in[3 * i + 2];
        } else {
            A[i] = (const float*)d_in[i];
            C[i] = (const float*)d_in[5 + i];
            R[i] = (const float*)d_in[10 + i];
        }
    }

    unsigned* keys   = (unsigned*)d_ws;
    unsigned* hist   = keys + NROWS;
    unsigned* coarse = hist + 4 * NBINS;     // adjacent: zeroed with hist
    unsigned* sel    = coarse + 4 * 1024;

    k_ruler<<<1530, 256, 0, stream>>>(C[0], C[1], C[2], C[3], keys, hist);
    k_hist<<<1024, 256, 0, stream>>>(keys, hist, coarse);
    k_select<<<4, 1024, 0, stream>>>(keys, hist, coarse, sel);
    k_epilogue<<<NSEL, 256, 0, stream>>>(A[0], A[1], A[2], A[3], A[4],
                                         C[0], C[1], C[2], C[3], C[4],
                                         R[0], R[1], R[2], R[3], R[4],
                                         sel, (float*)d_out);
}